// Round 10
// baseline (112.243 us; speedup 1.0000x reference)
//
#include <hip/hip_runtime.h>

// Fused SNN forward for MI355X (gfx950) — round 10.
// Regime re-read: VALUBusy ~88% is a gfx94x-formula artifact (4cy/instr vs
// gfx950's 2) -> real VALU busy ~44%; kernel is LATENCY-bound at ~1.7
// blocks/CU. So amortize per-block overhead: each block processes
// IMG_PER_BLK=4 images. fc-weight gather (30 global loads), unit geometry
// (magic divides), and sred constants are computed ONCE; per image only
// {stage sx, conv, 16-t loop, reduce, scan}. Main loop identical to r9
// (packed pk_fma math + permlane/DPP reduce, 3 DS writes/t/wave).

typedef float v2f __attribute__((ext_vector_type(2)));
typedef unsigned v2u __attribute__((ext_vector_type(2)));

#if __has_builtin(__builtin_elementwise_fma)
#define VFMA(a, b, c) __builtin_elementwise_fma((a), (b), (c))
#else
#define VFMA(a, b, c) ((a) * (b) + (c))
#endif

#define IMG_PER_BLK 4

// x + x[lane^16]  (VALU permlane, no LDS traffic)
__device__ __forceinline__ float bfly16(float x) {
#if __has_builtin(__builtin_amdgcn_permlane16_swap)
    v2u r = __builtin_amdgcn_permlane16_swap(__float_as_uint(x), __float_as_uint(x),
                                             false, false);
    return __uint_as_float(r.x) + __uint_as_float(r.y);
#else
    return x + __shfl_xor(x, 16);
#endif
}

// Fused fold + xor16: (lane&16)==0 ? a + a[l^16] : b + b[l^16].
// The SUM of permlane16_swap's two outputs is row-symmetric, so dst role
// ambiguity cancels.
__device__ __forceinline__ float pairfold16(float a, float b) {
#if __has_builtin(__builtin_amdgcn_permlane16_swap)
    v2u r = __builtin_amdgcn_permlane16_swap(__float_as_uint(a), __float_as_uint(b),
                                             false, false);
    return __uint_as_float(r.x) + __uint_as_float(r.y);
#else
    const float sa = a + __shfl_xor(a, 16);
    const float sb = b + __shfl_xor(b, 16);
    return ((threadIdx.x & 16) != 0) ? sb : sa;
#endif
}

// value held by lane^32 via v_permlane32_swap
__device__ __forceinline__ float partner32(float x, bool hi) {
#if __has_builtin(__builtin_amdgcn_permlane32_swap)
    v2u r = __builtin_amdgcn_permlane32_swap(__float_as_uint(x), __float_as_uint(x),
                                             false, false);
    return __uint_as_float(hi ? r.x : r.y);
#else
    (void)hi;
    return __shfl_xor(x, 32);
#endif
}

// x + row_ror:N(x) within each 16-lane row. N=8 == xor8; N=4 after the
// N=8 level (values period-8) == xor4.
template<int N>
__device__ __forceinline__ float dpp_ror_add(float x) {
#if __has_builtin(__builtin_amdgcn_update_dpp)
    int y = __builtin_amdgcn_update_dpp(0, __float_as_int(x), 0x120 + N, 0xf, 0xf, false);
    return x + __int_as_float(y);
#else
    return x + __shfl_xor(x, N);
#endif
}

__global__ __launch_bounds__(512, 4) void snn_fused_kernel(
    const float* __restrict__ x,       // [4096, 1, 28, 28]
    const float* __restrict__ conv_w,  // [8, 1, 3, 3]
    const float* __restrict__ fc_w,    // [10, 1352]
    float* __restrict__ out)           // [4096, 10]
{
    const int tid  = threadIdx.x;
    const int lane = tid & 63;
    const int wid  = tid >> 6;
    const int b0   = blockIdx.x * IMG_PER_BLK;

    __shared__ float sx[784];            // 28x28 image (reused per image)
    __shared__ float scw[72];            // conv weights
    __shared__ float sred[32 * 165];     // 32 rows x (16t*10o), stride 165
    __shared__ float scur2[160];         // [t][o]

    if (tid < 72) scw[tid] = conv_w[tid];

    const bool hi32 = (lane & 32) != 0;

    // ---- hoisted per-thread unit geometry (image-independent) ----
    int  xbase[3], kbase[3];
    bool uvalid[3];
    #pragma unroll
    for (int i = 0; i < 3; ++i) {
        const int u      = tid + 512 * i;
        const bool valid = (u < 1352);
        const int uu  = valid ? u : 0;
        const int k   = uu / 169;          // channel
        const int rem = uu - k * 169;
        const int pr  = rem / 13;          // pool row
        const int pc  = rem - pr * 13;     // pool col
        xbase[i]  = (2 * pr) * 28 + 2 * pc;
        kbase[i]  = k * 9;
        uvalid[i] = valid;
    }

    // ---- fc weights once per block (image-independent) ----
    v2f wl01[6], wl23[6];  // 0.25*fc_w for outputs {k0,k1},{k2,k3}
    float wl4[6];          // output k4
    #pragma unroll
    for (int j = 0; j < 6; ++j) {
        const int bt     = (j < 3) ? tid : (tid ^ 32);
        const int u      = bt + 512 * (j % 3);
        const bool valid = (u < 1352);
        const int uu     = valid ? u : 0;
        const int ob     = hi32 ? 5 : 0;
        const float sc   = valid ? 0.25f : 0.0f;
        wl01[j] = (v2f){sc * fc_w[(ob + 0) * 1352 + uu], sc * fc_w[(ob + 1) * 1352 + uu]};
        wl23[j] = (v2f){sc * fc_w[(ob + 2) * 1352 + uu], sc * fc_w[(ob + 3) * 1352 + uu]};
        wl4[j]  = sc * fc_w[(ob + 4) * 1352 + uu];
    }

    const v2f half2 = (v2f){0.5f, 0.5f};

    v2f cur2[3][2];   // conv out: [unit][{cells01, cells23}]
    v2f mem2[3][2];   // LIF-1 membranes

    // stageA: packed LIF on own units + permlane count exchange + packed FC
    auto stageA = [&](v2f& nv01, v2f& nv23, float& nv4) {
        float c[3];
        #pragma unroll
        for (int i = 0; i < 3; ++i) {
            v2f m01 = VFMA(half2, mem2[i][0], cur2[i][0]);
            v2f m23 = VFMA(half2, mem2[i][1], cur2[i][1]);
            v2f sp01, sp23;
            sp01.x = m01.x > 1.0f ? 1.0f : 0.0f;   // spike iff m > THR
            sp01.y = m01.y > 1.0f ? 1.0f : 0.0f;
            sp23.x = m23.x > 1.0f ? 1.0f : 0.0f;
            sp23.y = m23.y > 1.0f ? 1.0f : 0.0f;
            mem2[i][0] = m01 - sp01;               // subtract-reset (bit-identical)
            mem2[i][1] = m23 - sp23;
            v2f s = sp01 + sp23;
            c[i] = s.x + s.y;                      // 0..4 exact
        }
        float p[3];
        p[0] = partner32(c[0], hi32);
        p[1] = partner32(c[1], hi32);
        p[2] = partner32(c[2], hi32);

        nv01 = (v2f){0.0f, 0.0f};
        nv23 = (v2f){0.0f, 0.0f};
        nv4  = 0.0f;
        #pragma unroll
        for (int i = 0; i < 3; ++i) {              // own units (hide swap latency)
            const v2f f2 = (v2f){c[i], c[i]};      // folds into pk op_sel
            nv01 = VFMA(wl01[i], f2, nv01);
            nv23 = VFMA(wl23[i], f2, nv23);
            nv4  = __builtin_fmaf(wl4[i], c[i], nv4);
        }
        #pragma unroll
        for (int i = 0; i < 3; ++i) {              // partner units
            const v2f f2 = (v2f){p[i], p[i]};
            nv01 = VFMA(wl01[3 + i], f2, nv01);
            nv23 = VFMA(wl23[3 + i], f2, nv23);
            nv4  = __builtin_fmaf(wl4[3 + i], p[i], nv4);
        }
    };

    const int q   = lane >> 4;                     // quadrant 0..3
    const int bo  = (q & 1) * 2 + (q >> 1) * 5;    // {0,2,5,7}
    const int to  = 4 + (q >> 1) * 5;              // {4,4,9,9}
    const int row = wid * 4 + (lane & 3);          // 32 rows total

    #pragma unroll 1
    for (int img = 0; img < IMG_PER_BLK; ++img) {
        __syncthreads();   // (1) fence sx/sred reuse vs prior image's tail

        // ---- stage image ----
        {
            const float4* xg  = reinterpret_cast<const float4*>(x + (size_t)(b0 + img) * 784);
            float4*       sx4 = reinterpret_cast<float4*>(sx);
            if (tid < 196) sx4[tid] = xg[tid];
        }
        __syncthreads();   // (2) sx ready

        // ---- conv -> cur2, reset mem2 ----
        #pragma unroll
        for (int i = 0; i < 3; ++i) {
            float cw[9];
            #pragma unroll
            for (int qq = 0; qq < 9; ++qq) cw[qq] = scw[kbase[i] + qq];

            float xr[4][4];
            #pragma unroll
            for (int r = 0; r < 4; ++r) {
                const float2* rowp = reinterpret_cast<const float2*>(&sx[xbase[i] + r * 28]);
                const float2 a = rowp[0], c2 = rowp[1];
                xr[r][0] = a.x; xr[r][1] = a.y; xr[r][2] = c2.x; xr[r][3] = c2.y;
            }

            float cell[2][2];
            #pragma unroll
            for (int dr = 0; dr < 2; ++dr)
                #pragma unroll
                for (int dc = 0; dc < 2; ++dc) {
                    float acc = 0.0f;
                    #pragma unroll
                    for (int ki = 0; ki < 3; ++ki)
                        #pragma unroll
                        for (int kj = 0; kj < 3; ++kj)
                            acc += xr[dr + ki][dc + kj] * cw[ki * 3 + kj];
                    cell[dr][dc] = uvalid[i] ? acc : 0.0f;
                }
            cur2[i][0] = (v2f){cell[0][0], cell[0][1]};
            cur2[i][1] = (v2f){cell[1][0], cell[1][1]};
            mem2[i][0] = (v2f){0.0f, 0.0f};
            mem2[i][1] = (v2f){0.0f, 0.0f};
        }

        // ---- 16 timesteps, no barriers ----
        v2f v01, v23; float v4;
        stageA(v01, v23, v4);                      // t = 0 partials

        #pragma unroll
        for (int t = 0; t < 16; ++t) {
            // fused fold + xor16 (1 permlane + 1 add each)
            float w0 = pairfold16(v01.x, v23.x);
            float w1 = pairfold16(v01.y, v23.y);
            float w2 = bfly16(v4);

            v2f nv01, nv23; float nv4;
            if (t < 15) {
                stageA(nv01, nv23, nv4);
            } else {
                nv01 = (v2f){0.0f, 0.0f};
                nv23 = (v2f){0.0f, 0.0f};
                nv4  = 0.0f;
            }

            // xor8 / xor4 via DPP row_ror adds
            w0 = dpp_ror_add<8>(w0);
            w1 = dpp_ror_add<8>(w1);
            w2 = dpp_ror_add<8>(w2);
            w0 = dpp_ror_add<4>(w0);
            w1 = dpp_ror_add<4>(w1);
            w2 = dpp_ror_add<4>(w2);

            // 4 rows per wave; duplicate equal-value writes of w2 are benign
            if ((lane & 12) == 0) {
                const int base = row * 165 + t * 10;
                sred[base + bo]     = w0;
                sred[base + bo + 1] = w1;
                sred[base + to]     = w2;
            }

            v01 = nv01; v23 = nv23; v4 = nv4;
        }
        __syncthreads();   // (3) sred complete

        // ---- final reduce: 160 threads, one (t,o) each, 32 rows ----
        if (tid < 160) {
            float sum = 0.0f;
            #pragma unroll
            for (int r = 0; r < 32; ++r)
                sum += sred[r * 165 + tid];
            scur2[tid] = sum;
        }
        __syncthreads();   // (4) scur2 ready

        // ---- LIF-2 scan, 10 lanes ----
        if (tid < 10) {
            float m2 = 0.0f, cnt = 0.0f;
            #pragma unroll
            for (int t = 0; t < 16; ++t) {
                m2 = __builtin_fmaf(0.5f, m2, scur2[t * 10 + tid]);
                float ms = m2 - 1.0f;
                bool  sp = ms > 0.0f;
                m2  = sp ? ms : m2;
                cnt += sp ? 1.0f : 0.0f;
            }
            out[(size_t)(b0 + img) * 10 + tid] = cnt;
        }
    }
}

extern "C" void kernel_launch(void* const* d_in, const int* in_sizes, int n_in,
                              void* d_out, int out_size, void* d_ws, size_t ws_size,
                              hipStream_t stream) {
    const float* x      = (const float*)d_in[0];  // 4096*784
    const float* conv_w = (const float*)d_in[1];  // 72
    const float* fc_w   = (const float*)d_in[2];  // 13520
    float* out          = (float*)d_out;          // 40960

    const int B = in_sizes[0] / 784;              // 4096
    snn_fused_kernel<<<B / IMG_PER_BLK, 512, 0, stream>>>(x, conv_w, fc_w, out);
}

// Round 11
// 89.190 us; speedup vs baseline: 1.2585x; 1.2585x over previous
//
#include <hip/hip_runtime.h>

// Fused SNN forward for MI355X (gfx950) — round 11.
// Geometry probe per r10 decision rule: 256 threads/block (4 waves),
// 6 units/thread, NO output-split. Each thread accumulates all 10 FC
// outputs for its own 6 units (5 v2f pk_fma accumulators) -> the xor32
// count exchange disappears; the xor32 level joins the reduce tree as 5
// dual-register pairfold32 ops. Conv reads patches DIRECTLY from global
// (no sx staging, no staging barrier, no conv LDS bank conflicts).
// sred: 16 rows x 165. launch_bounds(256,3) caps VGPR ~170 (no spills).

typedef float v2f __attribute__((ext_vector_type(2)));
typedef unsigned v2u __attribute__((ext_vector_type(2)));

#if __has_builtin(__builtin_elementwise_fma)
#define VFMA(a, b, c) __builtin_elementwise_fma((a), (b), (c))
#else
#define VFMA(a, b, c) ((a) * (b) + (c))
#endif

#define NU 6   // units per thread (256 * 6 = 1536 >= 1352)

// x + x[lane^16]  (VALU permlane, no LDS traffic)
__device__ __forceinline__ float bfly16(float x) {
#if __has_builtin(__builtin_amdgcn_permlane16_swap)
    v2u r = __builtin_amdgcn_permlane16_swap(__float_as_uint(x), __float_as_uint(x),
                                             false, false);
    return __uint_as_float(r.x) + __uint_as_float(r.y);
#else
    return x + __shfl_xor(x, 16);
#endif
}

// (lane&16)==0 ? a + a[l^16] : b + b[l^16]  — sum of permlane16_swap's two
// outputs is row-symmetric, so dst role ambiguity cancels. (r9-validated.)
__device__ __forceinline__ float pairfold16(float a, float b) {
#if __has_builtin(__builtin_amdgcn_permlane16_swap)
    v2u r = __builtin_amdgcn_permlane16_swap(__float_as_uint(a), __float_as_uint(b),
                                             false, false);
    return __uint_as_float(r.x) + __uint_as_float(r.y);
#else
    const float sa = a + __shfl_xor(a, 16);
    const float sb = b + __shfl_xor(b, 16);
    return ((threadIdx.x & 16) != 0) ? sb : sa;
#endif
}

// (lane&32)==0 ? a + a[l^32] : b + b[l^32]  — same trick at width 32.
__device__ __forceinline__ float pairfold32(float a, float b) {
#if __has_builtin(__builtin_amdgcn_permlane32_swap)
    v2u r = __builtin_amdgcn_permlane32_swap(__float_as_uint(a), __float_as_uint(b),
                                             false, false);
    return __uint_as_float(r.x) + __uint_as_float(r.y);
#else
    const float sa = a + __shfl_xor(a, 32);
    const float sb = b + __shfl_xor(b, 32);
    return ((threadIdx.x & 32) != 0) ? sb : sa;
#endif
}

// x + row_ror:N(x) within each 16-lane row. N=8 == xor8; N=4 after the
// N=8 level (values period-8) == xor4.
template<int N>
__device__ __forceinline__ float dpp_ror_add(float x) {
#if __has_builtin(__builtin_amdgcn_update_dpp)
    int y = __builtin_amdgcn_update_dpp(0, __float_as_int(x), 0x120 + N, 0xf, 0xf, false);
    return x + __int_as_float(y);
#else
    return x + __shfl_xor(x, N);
#endif
}

__global__ __launch_bounds__(256, 3) void snn_fused_kernel(
    const float* __restrict__ x,       // [4096, 1, 28, 28]
    const float* __restrict__ conv_w,  // [8, 1, 3, 3]
    const float* __restrict__ fc_w,    // [10, 1352]
    float* __restrict__ out)           // [4096, 10]
{
    const int b    = blockIdx.x;
    const int tid  = threadIdx.x;
    const int lane = tid & 63;
    const int wid  = tid >> 6;         // 0..3

    __shared__ float scw[72];          // conv weights
    __shared__ float sred[16 * 165];   // 16 rows x (16t*10o), stride 165
    __shared__ float scur2[160];       // [t][o]

    if (tid < 72) scw[tid] = conv_w[tid];

    // ---- per-thread unit geometry + fc weights (all 10 outputs, own units) ----
    int xbase[NU], kbase[NU];
    v2f wl[NU][5];                     // 0.25*fc_w outputs {2j,2j+1}
    #pragma unroll
    for (int i = 0; i < NU; ++i) {
        const int u      = tid + 256 * i;
        const bool valid = (u < 1352);
        const int uu  = valid ? u : 0;
        const int k   = uu / 169;          // channel
        const int rem = uu - k * 169;
        const int pr  = rem / 13;          // pool row
        const int pc  = rem - pr * 13;     // pool col
        xbase[i] = 56 * pr + 2 * pc;       // (2pr)*28 + 2pc
        kbase[i] = 9 * k;
        const float sc = valid ? 0.25f : 0.0f;
        #pragma unroll
        for (int j = 0; j < 5; ++j)
            wl[i][j] = (v2f){sc * fc_w[(2 * j) * 1352 + uu],
                             sc * fc_w[(2 * j + 1) * 1352 + uu]};
    }
    __syncthreads();                   // scw ready

    // ---- conv straight from global (3 KB image, L2/L3-resident) ----
    const float* xb = x + (size_t)b * 784;
    v2f cur2[NU][2];   // conv out: [unit][{cells01, cells23}]
    v2f mem2[NU][2];   // LIF-1 membranes
    #pragma unroll
    for (int i = 0; i < NU; ++i) {
        float cw[9];
        #pragma unroll
        for (int qq = 0; qq < 9; ++qq) cw[qq] = scw[kbase[i] + qq];

        float xr[4][4];
        #pragma unroll
        for (int r = 0; r < 4; ++r) {
            const float2* rp = reinterpret_cast<const float2*>(xb + xbase[i] + 28 * r);
            const float2 a = rp[0], c2 = rp[1];
            xr[r][0] = a.x; xr[r][1] = a.y; xr[r][2] = c2.x; xr[r][3] = c2.y;
        }

        const bool valid = (tid + 256 * i) < 1352;
        float cell[2][2];
        #pragma unroll
        for (int dr = 0; dr < 2; ++dr)
            #pragma unroll
            for (int dc = 0; dc < 2; ++dc) {
                float acc = 0.0f;
                #pragma unroll
                for (int ki = 0; ki < 3; ++ki)
                    #pragma unroll
                    for (int kj = 0; kj < 3; ++kj)
                        acc += xr[dr + ki][dc + kj] * cw[ki * 3 + kj];
                cell[dr][dc] = valid ? acc : 0.0f;
            }
        cur2[i][0] = (v2f){cell[0][0], cell[0][1]};
        cur2[i][1] = (v2f){cell[1][0], cell[1][1]};
        mem2[i][0] = (v2f){0.0f, 0.0f};
        mem2[i][1] = (v2f){0.0f, 0.0f};
    }

    const v2f half2 = (v2f){0.5f, 0.5f};

    // stageA: packed LIF on 6 own units + 30 pk_fma into 5 v2f accumulators
    auto stageA = [&](v2f& a01, v2f& a23, v2f& a45, v2f& a67, v2f& a89) {
        a01 = a23 = a45 = a67 = a89 = (v2f){0.0f, 0.0f};
        #pragma unroll
        for (int i = 0; i < NU; ++i) {
            v2f m01 = VFMA(half2, mem2[i][0], cur2[i][0]);
            v2f m23 = VFMA(half2, mem2[i][1], cur2[i][1]);
            v2f sp01, sp23;
            sp01.x = m01.x > 1.0f ? 1.0f : 0.0f;   // spike iff m > THR
            sp01.y = m01.y > 1.0f ? 1.0f : 0.0f;
            sp23.x = m23.x > 1.0f ? 1.0f : 0.0f;
            sp23.y = m23.y > 1.0f ? 1.0f : 0.0f;
            mem2[i][0] = m01 - sp01;               // subtract-reset (bit-identical)
            mem2[i][1] = m23 - sp23;
            v2f s = sp01 + sp23;
            const float c = s.x + s.y;             // 0..4 exact
            const v2f f2 = (v2f){c, c};            // folds into pk op_sel
            a01 = VFMA(wl[i][0], f2, a01);
            a23 = VFMA(wl[i][1], f2, a23);
            a45 = VFMA(wl[i][2], f2, a45);
            a67 = VFMA(wl[i][3], f2, a67);
            a89 = VFMA(wl[i][4], f2, a89);
        }
    };

    v2f v01, v23, v45, v67, v89;
    stageA(v01, v23, v45, v67, v89);               // t = 0 partials

    const int q   = lane >> 4;                     // quadrant 0..3
    const int bo  = (q & 1) * 2 + (q >> 1) * 5;    // {0,2,5,7}
    const int to  = 4 + (q >> 1) * 5;              // {4,4,9,9}
    const int row = wid * 4 + (lane & 3);          // 16 rows total

    #pragma unroll
    for (int t = 0; t < 16; ++t) {
        // xor32 level: pair outputs (k, k+5) via dual-register permlane32
        const float s0 = pairfold32(v01.x, v45.y);
        const float s1 = pairfold32(v01.y, v67.x);
        const float s2 = pairfold32(v23.x, v67.y);
        const float s3 = pairfold32(v23.y, v89.x);
        const float s4 = pairfold32(v45.x, v89.y);
        // xor16 level: fold 5 -> 3
        float w0 = pairfold16(s0, s2);
        float w1 = pairfold16(s1, s3);
        float w2 = bfly16(s4);

        v2f n01, n23, n45, n67, n89;
        if (t < 15) {
            stageA(n01, n23, n45, n67, n89);       // hides permlane latency
        } else {
            n01 = n23 = n45 = n67 = n89 = (v2f){0.0f, 0.0f};
        }

        // xor8 / xor4 via DPP row_ror adds
        w0 = dpp_ror_add<8>(w0);
        w1 = dpp_ror_add<8>(w1);
        w2 = dpp_ror_add<8>(w2);
        w0 = dpp_ror_add<4>(w0);
        w1 = dpp_ror_add<4>(w1);
        w2 = dpp_ror_add<4>(w2);

        // 4 rows per wave; duplicate equal-value writes of w2 are benign
        if ((lane & 12) == 0) {
            const int base = row * 165 + t * 10;
            sred[base + bo]     = w0;
            sred[base + bo + 1] = w1;
            sred[base + to]     = w2;
        }

        v01 = n01; v23 = n23; v45 = n45; v67 = n67; v89 = n89;
    }
    __syncthreads();

    // ---- final reduce: 160 threads, one (t,o) each, 16 rows ----
    if (tid < 160) {
        float sum = 0.0f;
        #pragma unroll
        for (int r = 0; r < 16; ++r)
            sum += sred[r * 165 + tid];
        scur2[tid] = sum;
    }
    __syncthreads();

    // ---- LIF-2 scan, 10 lanes ----
    if (tid < 10) {
        float m2 = 0.0f, cnt = 0.0f;
        #pragma unroll
        for (int t = 0; t < 16; ++t) {
            m2 = __builtin_fmaf(0.5f, m2, scur2[t * 10 + tid]);
            float ms = m2 - 1.0f;
            bool  sp = ms > 0.0f;
            m2  = sp ? ms : m2;
            cnt += sp ? 1.0f : 0.0f;
        }
        out[(size_t)b * 10 + tid] = cnt;
    }
}

extern "C" void kernel_launch(void* const* d_in, const int* in_sizes, int n_in,
                              void* d_out, int out_size, void* d_ws, size_t ws_size,
                              hipStream_t stream) {
    const float* x      = (const float*)d_in[0];  // 4096*784
    const float* conv_w = (const float*)d_in[1];  // 72
    const float* fc_w   = (const float*)d_in[2];  // 13520
    float* out          = (float*)d_out;          // 40960

    const int B = in_sizes[0] / 784;              // 4096
    snn_fused_kernel<<<B, 256, 0, stream>>>(x, conv_w, fc_w, out);
}

// Round 12
// 88.108 us; speedup vs baseline: 1.2739x; 1.0123x over previous
//
#include <hip/hip_runtime.h>

// Fused SNN forward for MI355X (gfx950) — round 12.
// r11 + REGISTER-PINNING probe. r11's VGPR_Count=76 vs >=108 loop-live floats
// (and r9: 48 vs ~74) => the allocator is NOT keeping fc-weights in arch
// VGPRs: it either re-loads wl from global (L2-resident, invisible in
// FETCH_SIZE which counts HBM only) every t-iteration, or parks it in AGPRs
// (v_accvgpr_read per use). Both inflate t-loop latency/ops and explain the
// ~30% issue efficiency. Fix: pin all 30 wl values in VGPRs via empty asm
// "+v" constraints (non-rematerializable, VGPR-only, zero runtime cost).
// Also: w0/w1 LDS stores merged into one ds_write_b64.

typedef float v2f __attribute__((ext_vector_type(2)));
typedef unsigned v2u __attribute__((ext_vector_type(2)));

#if __has_builtin(__builtin_elementwise_fma)
#define VFMA(a, b, c) __builtin_elementwise_fma((a), (b), (c))
#else
#define VFMA(a, b, c) ((a) * (b) + (c))
#endif

#define NU 6   // units per thread (256 * 6 = 1536 >= 1352)

// x + x[lane^16]  (VALU permlane, no LDS traffic)
__device__ __forceinline__ float bfly16(float x) {
#if __has_builtin(__builtin_amdgcn_permlane16_swap)
    v2u r = __builtin_amdgcn_permlane16_swap(__float_as_uint(x), __float_as_uint(x),
                                             false, false);
    return __uint_as_float(r.x) + __uint_as_float(r.y);
#else
    return x + __shfl_xor(x, 16);
#endif
}

// (lane&16)==0 ? a + a[l^16] : b + b[l^16]  — sum of permlane16_swap's two
// outputs is row-symmetric, so dst role ambiguity cancels. (r9-validated.)
__device__ __forceinline__ float pairfold16(float a, float b) {
#if __has_builtin(__builtin_amdgcn_permlane16_swap)
    v2u r = __builtin_amdgcn_permlane16_swap(__float_as_uint(a), __float_as_uint(b),
                                             false, false);
    return __uint_as_float(r.x) + __uint_as_float(r.y);
#else
    const float sa = a + __shfl_xor(a, 16);
    const float sb = b + __shfl_xor(b, 16);
    return ((threadIdx.x & 16) != 0) ? sb : sa;
#endif
}

// (lane&32)==0 ? a + a[l^32] : b + b[l^32]  — same trick at width 32.
// (r11-validated.)
__device__ __forceinline__ float pairfold32(float a, float b) {
#if __has_builtin(__builtin_amdgcn_permlane32_swap)
    v2u r = __builtin_amdgcn_permlane32_swap(__float_as_uint(a), __float_as_uint(b),
                                             false, false);
    return __uint_as_float(r.x) + __uint_as_float(r.y);
#else
    const float sa = a + __shfl_xor(a, 32);
    const float sb = b + __shfl_xor(b, 32);
    return ((threadIdx.x & 32) != 0) ? sb : sa;
#endif
}

// x + row_ror:N(x) within each 16-lane row. N=8 == xor8; N=4 after the
// N=8 level (values period-8) == xor4.
template<int N>
__device__ __forceinline__ float dpp_ror_add(float x) {
#if __has_builtin(__builtin_amdgcn_update_dpp)
    int y = __builtin_amdgcn_update_dpp(0, __float_as_int(x), 0x120 + N, 0xf, 0xf, false);
    return x + __int_as_float(y);
#else
    return x + __shfl_xor(x, N);
#endif
}

__global__ __launch_bounds__(256, 3) void snn_fused_kernel(
    const float* __restrict__ x,       // [4096, 1, 28, 28]
    const float* __restrict__ conv_w,  // [8, 1, 3, 3]
    const float* __restrict__ fc_w,    // [10, 1352]
    float* __restrict__ out)           // [4096, 10]
{
    const int b    = blockIdx.x;
    const int tid  = threadIdx.x;
    const int lane = tid & 63;
    const int wid  = tid >> 6;         // 0..3

    __shared__ float scw[72];          // conv weights
    __shared__ float sred[16 * 165];   // 16 rows x (16t*10o), stride 165
    __shared__ float scur2[160];       // [t][o]

    if (tid < 72) scw[tid] = conv_w[tid];

    // ---- per-thread unit geometry + fc weights (all 10 outputs, own units) ----
    int xbase[NU], kbase[NU];
    v2f wl[NU][5];                     // 0.25*fc_w outputs {2j,2j+1}
    #pragma unroll
    for (int i = 0; i < NU; ++i) {
        const int u      = tid + 256 * i;
        const bool valid = (u < 1352);
        const int uu  = valid ? u : 0;
        const int k   = uu / 169;          // channel
        const int rem = uu - k * 169;
        const int pr  = rem / 13;          // pool row
        const int pc  = rem - pr * 13;     // pool col
        xbase[i] = 56 * pr + 2 * pc;       // (2pr)*28 + 2pc
        kbase[i] = 9 * k;
        const float sc = valid ? 0.25f : 0.0f;
        #pragma unroll
        for (int j = 0; j < 5; ++j) {
            wl[i][j] = (v2f){sc * fc_w[(2 * j) * 1352 + uu],
                             sc * fc_w[(2 * j + 1) * 1352 + uu]};
            // PIN: force arch-VGPR residency; empty asm is free at runtime,
            // not rematerializable, and "v" excludes AGPR/global re-loads.
            asm("" : "+v"(wl[i][j]));
        }
    }
    __syncthreads();                   // scw ready

    // ---- conv straight from global (3 KB image, L2/L3-resident) ----
    const float* xb = x + (size_t)b * 784;
    v2f cur2[NU][2];   // conv out: [unit][{cells01, cells23}]
    v2f mem2[NU][2];   // LIF-1 membranes
    #pragma unroll
    for (int i = 0; i < NU; ++i) {
        float cw[9];
        #pragma unroll
        for (int qq = 0; qq < 9; ++qq) cw[qq] = scw[kbase[i] + qq];

        float xr[4][4];
        #pragma unroll
        for (int r = 0; r < 4; ++r) {
            const float2* rp = reinterpret_cast<const float2*>(xb + xbase[i] + 28 * r);
            const float2 a = rp[0], c2 = rp[1];
            xr[r][0] = a.x; xr[r][1] = a.y; xr[r][2] = c2.x; xr[r][3] = c2.y;
        }

        const bool valid = (tid + 256 * i) < 1352;
        float cell[2][2];
        #pragma unroll
        for (int dr = 0; dr < 2; ++dr)
            #pragma unroll
            for (int dc = 0; dc < 2; ++dc) {
                float acc = 0.0f;
                #pragma unroll
                for (int ki = 0; ki < 3; ++ki)
                    #pragma unroll
                    for (int kj = 0; kj < 3; ++kj)
                        acc += xr[dr + ki][dc + kj] * cw[ki * 3 + kj];
                cell[dr][dc] = valid ? acc : 0.0f;
            }
        cur2[i][0] = (v2f){cell[0][0], cell[0][1]};
        cur2[i][1] = (v2f){cell[1][0], cell[1][1]};
        asm("" : "+v"(cur2[i][0]));    // pin conv outputs too (remat = re-conv)
        asm("" : "+v"(cur2[i][1]));
        mem2[i][0] = (v2f){0.0f, 0.0f};
        mem2[i][1] = (v2f){0.0f, 0.0f};
    }

    const v2f half2 = (v2f){0.5f, 0.5f};

    // stageA: packed LIF on 6 own units + 30 pk_fma into 5 v2f accumulators
    auto stageA = [&](v2f& a01, v2f& a23, v2f& a45, v2f& a67, v2f& a89) {
        a01 = a23 = a45 = a67 = a89 = (v2f){0.0f, 0.0f};
        #pragma unroll
        for (int i = 0; i < NU; ++i) {
            v2f m01 = VFMA(half2, mem2[i][0], cur2[i][0]);
            v2f m23 = VFMA(half2, mem2[i][1], cur2[i][1]);
            v2f sp01, sp23;
            sp01.x = m01.x > 1.0f ? 1.0f : 0.0f;   // spike iff m > THR
            sp01.y = m01.y > 1.0f ? 1.0f : 0.0f;
            sp23.x = m23.x > 1.0f ? 1.0f : 0.0f;
            sp23.y = m23.y > 1.0f ? 1.0f : 0.0f;
            mem2[i][0] = m01 - sp01;               // subtract-reset (bit-identical)
            mem2[i][1] = m23 - sp23;
            v2f s = sp01 + sp23;
            const float c = s.x + s.y;             // 0..4 exact
            const v2f f2 = (v2f){c, c};            // folds into pk op_sel
            a01 = VFMA(wl[i][0], f2, a01);
            a23 = VFMA(wl[i][1], f2, a23);
            a45 = VFMA(wl[i][2], f2, a45);
            a67 = VFMA(wl[i][3], f2, a67);
            a89 = VFMA(wl[i][4], f2, a89);
        }
    };

    v2f v01, v23, v45, v67, v89;
    stageA(v01, v23, v45, v67, v89);               // t = 0 partials

    const int q   = lane >> 4;                     // quadrant 0..3
    const int bo  = (q & 1) * 2 + (q >> 1) * 5;    // {0,2,5,7}
    const int to  = 4 + (q >> 1) * 5;              // {4,4,9,9}
    const int row = wid * 4 + (lane & 3);          // 16 rows total

    #pragma unroll
    for (int t = 0; t < 16; ++t) {
        // xor32 level: pair outputs (k, k+5) via dual-register permlane32
        const float s0 = pairfold32(v01.x, v45.y);
        const float s1 = pairfold32(v01.y, v67.x);
        const float s2 = pairfold32(v23.x, v67.y);
        const float s3 = pairfold32(v23.y, v89.x);
        const float s4 = pairfold32(v45.x, v89.y);
        // xor16 level: fold 5 -> 3
        float w0 = pairfold16(s0, s2);
        float w1 = pairfold16(s1, s3);
        float w2 = bfly16(s4);

        v2f n01, n23, n45, n67, n89;
        if (t < 15) {
            stageA(n01, n23, n45, n67, n89);       // hides permlane latency
        } else {
            n01 = n23 = n45 = n67 = n89 = (v2f){0.0f, 0.0f};
        }

        // xor8 / xor4 via DPP row_ror adds
        w0 = dpp_ror_add<8>(w0);
        w1 = dpp_ror_add<8>(w1);
        w2 = dpp_ror_add<8>(w2);
        w0 = dpp_ror_add<4>(w0);
        w1 = dpp_ror_add<4>(w1);
        w2 = dpp_ror_add<4>(w2);

        // 4 rows per wave; w0/w1 contiguous -> one b64 store; w2 dup-benign
        if ((lane & 12) == 0) {
            const int base = row * 165 + t * 10;
            *reinterpret_cast<v2f*>(&sred[base + bo]) = (v2f){w0, w1};
            sred[base + to] = w2;
        }

        v01 = n01; v23 = n23; v45 = n45; v67 = n67; v89 = n89;
    }
    __syncthreads();

    // ---- final reduce: 160 threads, one (t,o) each, 16 rows ----
    if (tid < 160) {
        float sum = 0.0f;
        #pragma unroll
        for (int r = 0; r < 16; ++r)
            sum += sred[r * 165 + tid];
        scur2[tid] = sum;
    }
    __syncthreads();

    // ---- LIF-2 scan, 10 lanes ----
    if (tid < 10) {
        float m2 = 0.0f, cnt = 0.0f;
        #pragma unroll
        for (int t = 0; t < 16; ++t) {
            m2 = __builtin_fmaf(0.5f, m2, scur2[t * 10 + tid]);
            float ms = m2 - 1.0f;
            bool  sp = ms > 0.0f;
            m2  = sp ? ms : m2;
            cnt += sp ? 1.0f : 0.0f;
        }
        out[(size_t)b * 10 + tid] = cnt;
    }
}

extern "C" void kernel_launch(void* const* d_in, const int* in_sizes, int n_in,
                              void* d_out, int out_size, void* d_ws, size_t ws_size,
                              hipStream_t stream) {
    const float* x      = (const float*)d_in[0];  // 4096*784
    const float* conv_w = (const float*)d_in[1];  // 72
    const float* fc_w   = (const float*)d_in[2];  // 13520
    float* out          = (float*)d_out;          // 40960

    const int B = in_sizes[0] / 784;              // 4096
    snn_fused_kernel<<<B, 256, 0, stream>>>(x, conv_w, fc_w, out);
}